// Round 2
// baseline (395.874 us; speedup 1.0000x reference)
//
#include <hip/hip_runtime.h>

typedef unsigned short u16;
typedef __attribute__((ext_vector_type(8))) short bf16x8;
typedef __attribute__((ext_vector_type(4))) short bf16x4;
typedef __attribute__((ext_vector_type(4))) float f32x4;

#define MFMA16(a, b, c) __builtin_amdgcn_mfma_f32_16x16x32_bf16(a, b, c, 0, 0, 0)

__device__ __forceinline__ u16 f2bf(float x) {
    unsigned u = __float_as_uint(x);
    return (u16)((u + 0x7fffu + ((u >> 16) & 1u)) >> 16);
}

// ---------------------------------------------------------------------------
// fp32 -> bf16 flat cast. n must be a multiple of 8*256.
// ---------------------------------------------------------------------------
__global__ __launch_bounds__(256) void castk(const float* __restrict__ src, u16* __restrict__ dst) {
    const int i = (blockIdx.x * 256 + threadIdx.x) * 8;
    float4 a = *(const float4*)(src + i);
    float4 b = *(const float4*)(src + i + 4);
    bf16x8 v;
    v[0] = (short)f2bf(a.x); v[1] = (short)f2bf(a.y);
    v[2] = (short)f2bf(a.z); v[3] = (short)f2bf(a.w);
    v[4] = (short)f2bf(b.x); v[5] = (short)f2bf(b.y);
    v[6] = (short)f2bf(b.z); v[7] = (short)f2bf(b.w);
    *(bf16x8*)(dst + i) = v;
}

// ---------------------------------------------------------------------------
// fp32 src[r][c] -> bf16 dst[c][r], 64x64 LDS tiles. grid R/64*C/64, block 256
// ---------------------------------------------------------------------------
__global__ __launch_bounds__(256) void tkern(const float* __restrict__ src, u16* __restrict__ dst,
                                             int R, int C) {
    const int tC = C >> 6;
    const int tr = (blockIdx.x / tC) << 6;
    const int tc = (blockIdx.x % tC) << 6;
    __shared__ u16 ls[64 * 68];
    const int tid = threadIdx.x;
#pragma unroll
    for (int rep = 0; rep < 2; ++rep) {
        const int f = tid * 8 + rep * 2048;
        const int r = f >> 6, c = f & 63;  // c is a multiple of 8
        float4 a = *(const float4*)(src + (size_t)(tr + r) * C + tc + c);
        float4 b = *(const float4*)(src + (size_t)(tr + r) * C + tc + c + 4);
        bf16x4 lo, hi;
        lo[0] = (short)f2bf(a.x); lo[1] = (short)f2bf(a.y);
        lo[2] = (short)f2bf(a.z); lo[3] = (short)f2bf(a.w);
        hi[0] = (short)f2bf(b.x); hi[1] = (short)f2bf(b.y);
        hi[2] = (short)f2bf(b.z); hi[3] = (short)f2bf(b.w);
        *(bf16x4*)&ls[r * 68 + c] = lo;
        *(bf16x4*)&ls[r * 68 + c + 4] = hi;
    }
    __syncthreads();
#pragma unroll
    for (int rep = 0; rep < 2; ++rep) {
        const int f = tid * 8 + rep * 2048;
        const int rn = f >> 6, ck = f & 63;  // ck multiple of 8 -> ck+j <= 63
        bf16x8 v;
#pragma unroll
        for (int j = 0; j < 8; ++j) v[j] = (short)ls[(ck + j) * 68 + rn];
        *(bf16x8*)(dst + (size_t)(tc + rn) * R + tr + ck) = v;
    }
}

// ---------------------------------------------------------------------------
// GEMM: C[m][n] = sum_k A[m][k] * Bt[n][k] + bias[n].  M=8192, K=1024, bf16.
// MODE 0: N=3072, scatter to Q(scaled)[BH][T][D], K[BH][T][D], V^T[BH][D][T].
// MODE 1: N=1024, fp32 store to Of[M][N].
// 128x128 tile, BK=32, 256 threads (2x2 waves), global_load_lds width 16.
// ---------------------------------------------------------------------------
template <int MODE>
__global__ __launch_bounds__(256) void gemm_k(const u16* __restrict__ A, const u16* __restrict__ Bt,
                                              const float* __restrict__ bias,
                                              u16* __restrict__ Qo, u16* __restrict__ Ko,
                                              u16* __restrict__ Vo, float* __restrict__ Of) {
    constexpr int Kd = 1024;
    const int tid = threadIdx.x;
    const int lane = tid & 63, wave = tid >> 6;
    const int wm = wave >> 1, wn = wave & 1;
    const int lr = lane & 15, lg = lane >> 4;
    const int mt = blockIdx.x & 63;
    const int nt = blockIdx.x >> 6;
    const int mbase = mt << 7, nbase = nt << 7;
    __shared__ u16 As[128 * 32];
    __shared__ u16 Bs[128 * 32];
    f32x4 acc[4][4];
#pragma unroll
    for (int i = 0; i < 4; ++i)
#pragma unroll
        for (int j = 0; j < 4; ++j) acc[i][j] = {0.f, 0.f, 0.f, 0.f};

    for (int kb = 0; kb < Kd; kb += 32) {
        __syncthreads();
#pragma unroll
        for (int rep = 0; rep < 2; ++rep) {
            const int f = tid * 8 + rep * 2048;  // lane-contiguous 16B in LDS
            const int r = f >> 5, c = f & 31;
            __builtin_amdgcn_global_load_lds(
                (const __attribute__((address_space(1))) void*)(A + (size_t)(mbase + r) * Kd + kb + c),
                (__attribute__((address_space(3))) void*)(As + f), 16, 0, 0);
            __builtin_amdgcn_global_load_lds(
                (const __attribute__((address_space(1))) void*)(Bt + (size_t)(nbase + r) * Kd + kb + c),
                (__attribute__((address_space(3))) void*)(Bs + f), 16, 0, 0);
        }
        __syncthreads();
        bf16x8 af[4], bfr[4];
#pragma unroll
        for (int i = 0; i < 4; ++i)
            af[i] = *(const bf16x8*)&As[(wm * 64 + i * 16 + lr) * 32 + lg * 8];
#pragma unroll
        for (int j = 0; j < 4; ++j)
            bfr[j] = *(const bf16x8*)&Bs[(wn * 64 + j * 16 + lr) * 32 + lg * 8];
#pragma unroll
        for (int i = 0; i < 4; ++i)
#pragma unroll
            for (int j = 0; j < 4; ++j) acc[i][j] = MFMA16(af[i], bfr[j], acc[i][j]);
    }

    // epilogue: C-layout row = lg*4 + reg, col = lr (within each 16x16 tile)
    const float QSCALE = 0.1803368801111137f;  // 0.125 * log2(e), folded into Q
#pragma unroll
    for (int j = 0; j < 4; ++j) {
        const int n = nbase + wn * 64 + j * 16 + lr;
        const float bj = bias[n];
        if (MODE == 0) {
            const int three = n >> 10;       // 0=Q 1=K 2=V (uniform per j-tile)
            const int h = (n >> 6) & 15;
            const int d = n & 63;
#pragma unroll
            for (int i = 0; i < 4; ++i) {
#pragma unroll
                for (int r = 0; r < 4; ++r) {
                    const int m = mbase + wm * 64 + i * 16 + lg * 4 + r;
                    const int b = m >> 11, t = m & 2047;
                    const int bh = (b << 4) + h;
                    const float val = acc[i][j][r] + bj;
                    if (three == 0)
                        Qo[(((size_t)bh << 11) + t) * 64 + d] = f2bf(val * QSCALE);
                    else if (three == 1)
                        Ko[(((size_t)bh << 11) + t) * 64 + d] = f2bf(val);
                    else
                        Vo[(((size_t)bh << 6) + d) * 2048 + t] = f2bf(val);
                }
            }
        } else {
#pragma unroll
            for (int i = 0; i < 4; ++i) {
#pragma unroll
                for (int r = 0; r < 4; ++r) {
                    const int m = mbase + wm * 64 + i * 16 + lg * 4 + r;
                    Of[((size_t)m << 10) + n] = acc[i][j][r] + bj;
                }
            }
        }
    }
}

// ---------------------------------------------------------------------------
// Causal flash attention. Q,K: [BH][T][D] bf16 (Q pre-scaled by 0.125*log2e),
// Vt: [BH][D][T] bf16, Aout: [B][T][H*D] bf16. grid (T/64, B*H), block 256.
// S^T = K*Q^T keeps all MFMA operands k-contiguous; P round-trips LDS.
// ---------------------------------------------------------------------------
__global__ __launch_bounds__(256) void flash_attn(const u16* __restrict__ Q, const u16* __restrict__ Kg,
                                                  const u16* __restrict__ Vt, u16* __restrict__ Aout) {
    const int tid = threadIdx.x;
    const int lane = tid & 63, wave = tid >> 6;
    const int lr = lane & 15, lg = lane >> 4;
    const int qb = blockIdx.x;  // 0..31
    const int bh = blockIdx.y;  // 0..63
    const int b = bh >> 4, h = bh & 15;
    const size_t base = (size_t)bh << 17;  // bh * 2048 * 64

    __shared__ u16 Ks[64 * 72];
    __shared__ u16 Vs[64 * 72];
    __shared__ u16 Ps[4][16 * 72];

    const u16* Qrow = Q + base + (size_t)(qb * 64 + wave * 16 + lr) * 64;
    const bf16x8 qf0 = *(const bf16x8*)(Qrow + lg * 8);
    const bf16x8 qf1 = *(const bf16x8*)(Qrow + 32 + lg * 8);

    f32x4 o[4];
#pragma unroll
    for (int dt = 0; dt < 4; ++dt) o[dt] = {0.f, 0.f, 0.f, 0.f};
    float m_i = -INFINITY, l_i = 0.f;
    const int q_glob = qb * 64 + wave * 16 + lr;

    for (int kt = 0; kt <= qb; ++kt) {
        __syncthreads();
#pragma unroll
        for (int rep = 0; rep < 2; ++rep) {
            const int f = tid * 8 + rep * 2048;
            const int r = f >> 6, c = f & 63;
            *(bf16x8*)&Ks[r * 72 + c] = *(const bf16x8*)(Kg + base + (size_t)(kt * 64 + r) * 64 + c);
            *(bf16x8*)&Vs[r * 72 + c] = *(const bf16x8*)(Vt + base + (size_t)r * 2048 + kt * 64 + c);
        }
        __syncthreads();

        // S^T[kv][q] = K * Q^T
        f32x4 s[4];
#pragma unroll
        for (int rt = 0; rt < 4; ++rt) {
            const bf16x8 k0 = *(const bf16x8*)&Ks[(rt * 16 + lr) * 72 + lg * 8];
            const bf16x8 k1 = *(const bf16x8*)&Ks[(rt * 16 + lr) * 72 + 32 + lg * 8];
            f32x4 z = {0.f, 0.f, 0.f, 0.f};
            z = MFMA16(k0, qf0, z);
            z = MFMA16(k1, qf1, z);
            s[rt] = z;  // kv = rt*16 + lg*4 + reg, q = lr
        }
        if (kt == qb) {
#pragma unroll
            for (int rt = 0; rt < 4; ++rt)
#pragma unroll
                for (int r = 0; r < 4; ++r) {
                    const int kv = kt * 64 + rt * 16 + lg * 4 + r;
                    if (kv > q_glob) s[rt][r] = -INFINITY;
                }
        }
        float rmax = -INFINITY;
#pragma unroll
        for (int rt = 0; rt < 4; ++rt)
#pragma unroll
            for (int r = 0; r < 4; ++r) rmax = fmaxf(rmax, s[rt][r]);
        rmax = fmaxf(rmax, __shfl_xor(rmax, 16));
        rmax = fmaxf(rmax, __shfl_xor(rmax, 32));
        const float m_new = fmaxf(m_i, rmax);
        const float alpha = exp2f(m_i - m_new);
        float rsum = 0.f;
#pragma unroll
        for (int rt = 0; rt < 4; ++rt)
#pragma unroll
            for (int r = 0; r < 4; ++r) {
                const float p = exp2f(s[rt][r] - m_new);
                s[rt][r] = p;
                rsum += p;
            }
        rsum += __shfl_xor(rsum, 16);
        rsum += __shfl_xor(rsum, 32);
        l_i = l_i * alpha + rsum;
        m_i = m_new;

        // P -> LDS [q][kv]
#pragma unroll
        for (int rt = 0; rt < 4; ++rt) {
            bf16x4 pk;
#pragma unroll
            for (int r = 0; r < 4; ++r) pk[r] = (short)f2bf(s[rt][r]);
            *(bf16x4*)&Ps[wave][lr * 72 + rt * 16 + lg * 4] = pk;
        }
        float aq[4];
#pragma unroll
        for (int r = 0; r < 4; ++r) aq[r] = __shfl(alpha, (lane & 48) + lg * 4 + r);
#pragma unroll
        for (int dt = 0; dt < 4; ++dt)
#pragma unroll
            for (int r = 0; r < 4; ++r) o[dt][r] *= aq[r];

        const bf16x8 pf0 = *(const bf16x8*)&Ps[wave][lr * 72 + lg * 8];
        const bf16x8 pf1 = *(const bf16x8*)&Ps[wave][lr * 72 + 32 + lg * 8];
#pragma unroll
        for (int dt = 0; dt < 4; ++dt) {
            const bf16x8 v0 = *(const bf16x8*)&Vs[(dt * 16 + lr) * 72 + lg * 8];
            const bf16x8 v1 = *(const bf16x8*)&Vs[(dt * 16 + lr) * 72 + 32 + lg * 8];
            o[dt] = MFMA16(pf0, v0, o[dt]);
            o[dt] = MFMA16(pf1, v1, o[dt]);
        }
    }

    const float linv = 1.f / l_i;
    float lq[4];
#pragma unroll
    for (int r = 0; r < 4; ++r) lq[r] = __shfl(linv, (lane & 48) + lg * 4 + r);
#pragma unroll
    for (int dt = 0; dt < 4; ++dt)
#pragma unroll
        for (int r = 0; r < 4; ++r) {
            const int t = qb * 64 + wave * 16 + lg * 4 + r;
            Aout[(((size_t)(b << 11) + t) << 10) + h * 64 + dt * 16 + lr] = f2bf(o[dt][r] * lq[r]);
        }
}

// ---------------------------------------------------------------------------
extern "C" void kernel_launch(void* const* d_in, const int* in_sizes, int n_in,
                              void* d_out, int out_size, void* d_ws, size_t ws_size,
                              hipStream_t stream) {
    (void)in_sizes; (void)n_in; (void)out_size; (void)ws_size;
    const float* x    = (const float*)d_in[0];
    // d_in[1] = causal mask (unused; causality applied analytically)
    const float* Wqkv = (const float*)d_in[2];
    const float* bqkv = (const float*)d_in[3];
    const float* Wout = (const float*)d_in[4];
    const float* bout = (const float*)d_in[5];
    float* out = (float*)d_out;

    char* ws = (char*)d_ws;
    u16* WqkvT = (u16*)(ws);                    //  6 MB: [3072][1024] bf16
    u16* WoutT = (u16*)(ws + 6291456);          //  2 MB: [1024][1024] bf16
    u16* xb    = (u16*)(ws + 8388608);          // 16 MB: [8192][1024] bf16
    u16* Qb    = (u16*)(ws + 25165824);         // 16 MB: [BH][T][D]
    u16* Kb    = (u16*)(ws + 41943040);         // 16 MB: [BH][T][D]
    u16* Vtb   = (u16*)(ws + 58720256);         // 16 MB: [BH][D][T]
    u16* Ab    = (u16*)(ws + 75497472);         // 16 MB: [B][T][C]

    castk<<<dim3(4096), 256, 0, stream>>>(x, xb);
    tkern<<<dim3(16 * 48), 256, 0, stream>>>(Wqkv, WqkvT, 1024, 3072);
    tkern<<<dim3(16 * 16), 256, 0, stream>>>(Wout, WoutT, 1024, 1024);
    gemm_k<0><<<dim3(64 * 24), 256, 0, stream>>>(xb, WqkvT, bqkv, Qb, Kb, Vtb, nullptr);
    flash_attn<<<dim3(32, 64), 256, 0, stream>>>(Qb, Kb, Vtb, Ab);
    gemm_k<1><<<dim3(64 * 8), 256, 0, stream>>>(Ab, WoutT, bout, nullptr, nullptr, nullptr, out);
}

// Round 3
// 340.724 us; speedup vs baseline: 1.1619x; 1.1619x over previous
//
#include <hip/hip_runtime.h>

typedef unsigned short u16;
typedef __attribute__((ext_vector_type(8))) short bf16x8;
typedef __attribute__((ext_vector_type(4))) short bf16x4;
typedef __attribute__((ext_vector_type(4))) float f32x4;

#define MFMA16(a, b, c) __builtin_amdgcn_mfma_f32_16x16x32_bf16(a, b, c, 0, 0, 0)

__device__ __forceinline__ u16 f2bf(float x) {
    unsigned u = __float_as_uint(x);
    return (u16)((u + 0x7fffu + ((u >> 16) & 1u)) >> 16);
}

// ---------------------------------------------------------------------------
// fp32 -> bf16 flat cast. n must be a multiple of 8*256.
// ---------------------------------------------------------------------------
__global__ __launch_bounds__(256) void castk(const float* __restrict__ src, u16* __restrict__ dst) {
    const int i = (blockIdx.x * 256 + threadIdx.x) * 8;
    float4 a = *(const float4*)(src + i);
    float4 b = *(const float4*)(src + i + 4);
    bf16x8 v;
    v[0] = (short)f2bf(a.x); v[1] = (short)f2bf(a.y);
    v[2] = (short)f2bf(a.z); v[3] = (short)f2bf(a.w);
    v[4] = (short)f2bf(b.x); v[5] = (short)f2bf(b.y);
    v[6] = (short)f2bf(b.z); v[7] = (short)f2bf(b.w);
    *(bf16x8*)(dst + i) = v;
}

// ---------------------------------------------------------------------------
// fp32 src[r][c] -> bf16 dst[c][r], 64x64 LDS tiles. grid R/64*C/64, block 256
// ---------------------------------------------------------------------------
__global__ __launch_bounds__(256) void tkern(const float* __restrict__ src, u16* __restrict__ dst,
                                             int R, int C) {
    const int tC = C >> 6;
    const int tr = (blockIdx.x / tC) << 6;
    const int tc = (blockIdx.x % tC) << 6;
    __shared__ u16 ls[64 * 68];
    const int tid = threadIdx.x;
#pragma unroll
    for (int rep = 0; rep < 2; ++rep) {
        const int f = tid * 8 + rep * 2048;
        const int r = f >> 6, c = f & 63;
        float4 a = *(const float4*)(src + (size_t)(tr + r) * C + tc + c);
        float4 b = *(const float4*)(src + (size_t)(tr + r) * C + tc + c + 4);
        bf16x4 lo, hi;
        lo[0] = (short)f2bf(a.x); lo[1] = (short)f2bf(a.y);
        lo[2] = (short)f2bf(a.z); lo[3] = (short)f2bf(a.w);
        hi[0] = (short)f2bf(b.x); hi[1] = (short)f2bf(b.y);
        hi[2] = (short)f2bf(b.z); hi[3] = (short)f2bf(b.w);
        *(bf16x4*)&ls[r * 68 + c] = lo;
        *(bf16x4*)&ls[r * 68 + c + 4] = hi;
    }
    __syncthreads();
#pragma unroll
    for (int rep = 0; rep < 2; ++rep) {
        const int f = tid * 8 + rep * 2048;
        const int rn = f >> 6, ck = f & 63;
        bf16x8 v;
#pragma unroll
        for (int j = 0; j < 8; ++j) v[j] = (short)ls[(ck + j) * 68 + rn];
        *(bf16x8*)(dst + (size_t)(tc + rn) * R + tr + ck) = v;
    }
}

// ---------------------------------------------------------------------------
// GEMM: C[m][n] = sum_k A[m][k] * Bt[n][k] + bias[n].  M=8192, K=1024, bf16.
// MODE 0: N=3072, scatter to Q(scaled)[BH][T][D], K[BH][T][D], V^T[BH][D][T].
// MODE 1: N=1024, fp32 store to Of[M][N].
// 128x128 tile, BK=32, 256 threads (2x2 waves), global_load_lds width 16.
// ---------------------------------------------------------------------------
template <int MODE>
__global__ __launch_bounds__(256) void gemm_k(const u16* __restrict__ A, const u16* __restrict__ Bt,
                                              const float* __restrict__ bias,
                                              u16* __restrict__ Qo, u16* __restrict__ Ko,
                                              u16* __restrict__ Vo, float* __restrict__ Of) {
    constexpr int Kd = 1024;
    const int tid = threadIdx.x;
    const int lane = tid & 63, wave = tid >> 6;
    const int wm = wave >> 1, wn = wave & 1;
    const int lr = lane & 15, lg = lane >> 4;
    const int mt = blockIdx.x & 63;
    const int nt = blockIdx.x >> 6;
    const int mbase = mt << 7, nbase = nt << 7;
    __shared__ u16 As[128 * 32];
    __shared__ u16 Bs[128 * 32];
    f32x4 acc[4][4];
#pragma unroll
    for (int i = 0; i < 4; ++i)
#pragma unroll
        for (int j = 0; j < 4; ++j) acc[i][j] = {0.f, 0.f, 0.f, 0.f};

    for (int kb = 0; kb < Kd; kb += 32) {
        __syncthreads();
#pragma unroll
        for (int rep = 0; rep < 2; ++rep) {
            const int f = tid * 8 + rep * 2048;
            const int r = f >> 5, c = f & 31;
            __builtin_amdgcn_global_load_lds(
                (const __attribute__((address_space(1))) void*)(A + (size_t)(mbase + r) * Kd + kb + c),
                (__attribute__((address_space(3))) void*)(As + f), 16, 0, 0);
            __builtin_amdgcn_global_load_lds(
                (const __attribute__((address_space(1))) void*)(Bt + (size_t)(nbase + r) * Kd + kb + c),
                (__attribute__((address_space(3))) void*)(Bs + f), 16, 0, 0);
        }
        __syncthreads();
        bf16x8 af[4], bfr[4];
#pragma unroll
        for (int i = 0; i < 4; ++i)
            af[i] = *(const bf16x8*)&As[(wm * 64 + i * 16 + lr) * 32 + lg * 8];
#pragma unroll
        for (int j = 0; j < 4; ++j)
            bfr[j] = *(const bf16x8*)&Bs[(wn * 64 + j * 16 + lr) * 32 + lg * 8];
#pragma unroll
        for (int i = 0; i < 4; ++i)
#pragma unroll
            for (int j = 0; j < 4; ++j) acc[i][j] = MFMA16(af[i], bfr[j], acc[i][j]);
    }

    const float QSCALE = 0.1803368801111137f;  // 0.125 * log2(e), folded into Q
#pragma unroll
    for (int j = 0; j < 4; ++j) {
        const int n = nbase + wn * 64 + j * 16 + lr;
        const float bj = bias[n];
        if (MODE == 0) {
            const int three = n >> 10;
            const int h = (n >> 6) & 15;
            const int d = n & 63;
#pragma unroll
            for (int i = 0; i < 4; ++i) {
#pragma unroll
                for (int r = 0; r < 4; ++r) {
                    const int m = mbase + wm * 64 + i * 16 + lg * 4 + r;
                    const int b = m >> 11, t = m & 2047;
                    const int bh = (b << 4) + h;
                    const float val = acc[i][j][r] + bj;
                    if (three == 0)
                        Qo[(((size_t)bh << 11) + t) * 64 + d] = f2bf(val * QSCALE);
                    else if (three == 1)
                        Ko[(((size_t)bh << 11) + t) * 64 + d] = f2bf(val);
                    else
                        Vo[(((size_t)bh << 6) + d) * 2048 + t] = f2bf(val);
                }
            }
        } else {
#pragma unroll
            for (int i = 0; i < 4; ++i) {
#pragma unroll
                for (int r = 0; r < 4; ++r) {
                    const int m = mbase + wm * 64 + i * 16 + lg * 4 + r;
                    Of[((size_t)m << 10) + n] = acc[i][j][r] + bj;
                }
            }
        }
    }
}

// ---------------------------------------------------------------------------
// Causal flash attention, BALANCED pair-tiling.
// Q,K: [BH][T][D] bf16 (Q pre-scaled by 0.125*log2e), Vt: [BH][D][T] bf16,
// Aout: [B][T][H*D] bf16.  grid (16, B*H), block 256.
// Block bx handles q-tiles qb_hi=16+bx and qb_lo=15-bx: every block does
// exactly 33 tile-processing iterations (perfect balance), and for
// kt <= qb_lo both tiles share one K/V LDS staging (saves ~half staging).
// ---------------------------------------------------------------------------
__global__ __launch_bounds__(256) void flash_attn(const u16* __restrict__ Q, const u16* __restrict__ Kg,
                                                  const u16* __restrict__ Vt, u16* __restrict__ Aout) {
    const int tid = threadIdx.x;
    const int lane = tid & 63, wave = tid >> 6;
    const int lr = lane & 15, lg = lane >> 4;
    const int bx = blockIdx.x;     // 0..15
    const int bh = blockIdx.y;     // 0..63
    const int b = bh >> 4, h = bh & 15;
    const size_t base = (size_t)bh << 17;  // bh * 2048 * 64

    const int qb_hi = 16 + bx;
    const int qb_lo = 15 - bx;

    __shared__ u16 Ks[64 * 72];
    __shared__ u16 Vs[64 * 72];
    __shared__ u16 Ps[4][16 * 72];

    // Q fragments for both tiles (B-frag: n=q(lr), k=d)
    const u16* QrowH = Q + base + (size_t)(qb_hi * 64 + wave * 16 + lr) * 64;
    const u16* QrowL = Q + base + (size_t)(qb_lo * 64 + wave * 16 + lr) * 64;
    const bf16x8 qh0 = *(const bf16x8*)(QrowH + lg * 8);
    const bf16x8 qh1 = *(const bf16x8*)(QrowH + 32 + lg * 8);
    const bf16x8 ql0 = *(const bf16x8*)(QrowL + lg * 8);
    const bf16x8 ql1 = *(const bf16x8*)(QrowL + 32 + lg * 8);

    f32x4 oh[4], ol[4];
#pragma unroll
    for (int dt = 0; dt < 4; ++dt) { oh[dt] = {0.f, 0.f, 0.f, 0.f}; ol[dt] = {0.f, 0.f, 0.f, 0.f}; }
    float m_hi = -INFINITY, l_hi = 0.f, m_lo = -INFINITY, l_lo = 0.f;
    const int qg_hi = qb_hi * 64 + wave * 16 + lr;
    const int qg_lo = qb_lo * 64 + wave * 16 + lr;

    // staging pointers (increment per kt to avoid re-deriving 64-bit addrs)
    const int f0 = tid * 8, f1 = tid * 8 + 2048;
    const u16* kp0 = Kg + base + (size_t)(f0 >> 6) * 64 + (f0 & 63);
    const u16* kp1 = Kg + base + (size_t)(f1 >> 6) * 64 + (f1 & 63);
    const u16* vp0 = Vt + base + (size_t)(f0 >> 6) * 2048 + (f0 & 63);
    const u16* vp1 = Vt + base + (size_t)(f1 >> 6) * 2048 + (f1 & 63);
    u16* ksd0 = &Ks[(f0 >> 6) * 72 + (f0 & 63)];
    u16* ksd1 = &Ks[(f1 >> 6) * 72 + (f1 & 63)];
    u16* vsd0 = &Vs[(f0 >> 6) * 72 + (f0 & 63)];
    u16* vsd1 = &Vs[(f1 >> 6) * 72 + (f1 & 63)];

    // process one q-tile against the currently staged K/V tile
    auto process = [&](const bf16x8& qf0, const bf16x8& qf1, f32x4* o,
                       float& m_i, float& l_i, int q_glob, int kvbase, bool diag) {
        f32x4 s[4];
#pragma unroll
        for (int rt = 0; rt < 4; ++rt) {
            const bf16x8 k0 = *(const bf16x8*)&Ks[(rt * 16 + lr) * 72 + lg * 8];
            const bf16x8 k1 = *(const bf16x8*)&Ks[(rt * 16 + lr) * 72 + 32 + lg * 8];
            f32x4 z = {0.f, 0.f, 0.f, 0.f};
            z = MFMA16(k0, qf0, z);
            z = MFMA16(k1, qf1, z);
            s[rt] = z;  // kv = kvbase + rt*16 + lg*4 + reg, q = lr
        }
        if (diag) {
#pragma unroll
            for (int rt = 0; rt < 4; ++rt)
#pragma unroll
                for (int r = 0; r < 4; ++r) {
                    const int kv = kvbase + rt * 16 + lg * 4 + r;
                    if (kv > q_glob) s[rt][r] = -INFINITY;
                }
        }
        float rmax = -INFINITY;
#pragma unroll
        for (int rt = 0; rt < 4; ++rt)
#pragma unroll
            for (int r = 0; r < 4; ++r) rmax = fmaxf(rmax, s[rt][r]);
        rmax = fmaxf(rmax, __shfl_xor(rmax, 16));
        rmax = fmaxf(rmax, __shfl_xor(rmax, 32));
        const float m_new = fmaxf(m_i, rmax);
        const float alpha = exp2f(m_i - m_new);
        float rsum = 0.f;
#pragma unroll
        for (int rt = 0; rt < 4; ++rt)
#pragma unroll
            for (int r = 0; r < 4; ++r) {
                const float p = exp2f(s[rt][r] - m_new);
                s[rt][r] = p;
                rsum += p;
            }
        rsum += __shfl_xor(rsum, 16);
        rsum += __shfl_xor(rsum, 32);
        l_i = l_i * alpha + rsum;
        m_i = m_new;

#pragma unroll
        for (int rt = 0; rt < 4; ++rt) {
            bf16x4 pk;
#pragma unroll
            for (int r = 0; r < 4; ++r) pk[r] = (short)f2bf(s[rt][r]);
            *(bf16x4*)&Ps[wave][lr * 72 + rt * 16 + lg * 4] = pk;
        }
        float aq[4];
#pragma unroll
        for (int r = 0; r < 4; ++r) aq[r] = __shfl(alpha, (lane & 48) + lg * 4 + r);
#pragma unroll
        for (int dt = 0; dt < 4; ++dt)
#pragma unroll
            for (int r = 0; r < 4; ++r) o[dt][r] *= aq[r];

        const bf16x8 pf0 = *(const bf16x8*)&Ps[wave][lr * 72 + lg * 8];
        const bf16x8 pf1 = *(const bf16x8*)&Ps[wave][lr * 72 + 32 + lg * 8];
#pragma unroll
        for (int dt = 0; dt < 4; ++dt) {
            const bf16x8 v0 = *(const bf16x8*)&Vs[(dt * 16 + lr) * 72 + lg * 8];
            const bf16x8 v1 = *(const bf16x8*)&Vs[(dt * 16 + lr) * 72 + 32 + lg * 8];
            o[dt] = MFMA16(pf0, v0, o[dt]);
            o[dt] = MFMA16(pf1, v1, o[dt]);
        }
    };

    for (int kt = 0; kt <= qb_hi; ++kt) {
        __syncthreads();
        *(bf16x8*)ksd0 = *(const bf16x8*)kp0;
        *(bf16x8*)ksd1 = *(const bf16x8*)kp1;
        *(bf16x8*)vsd0 = *(const bf16x8*)vp0;
        *(bf16x8*)vsd1 = *(const bf16x8*)vp1;
        kp0 += 4096; kp1 += 4096; vp0 += 64; vp1 += 64;
        __syncthreads();

        process(qh0, qh1, oh, m_hi, l_hi, qg_hi, kt * 64, kt == qb_hi);
        if (kt <= qb_lo) process(ql0, ql1, ol, m_lo, l_lo, qg_lo, kt * 64, kt == qb_lo);
    }

    // epilogue: both tiles
    {
        const float linv = 1.f / l_hi;
        float lq[4];
#pragma unroll
        for (int r = 0; r < 4; ++r) lq[r] = __shfl(linv, (lane & 48) + lg * 4 + r);
#pragma unroll
        for (int dt = 0; dt < 4; ++dt)
#pragma unroll
            for (int r = 0; r < 4; ++r) {
                const int t = qb_hi * 64 + wave * 16 + lg * 4 + r;
                Aout[(((size_t)(b << 11) + t) << 10) + h * 64 + dt * 16 + lr] = f2bf(oh[dt][r] * lq[r]);
            }
    }
    {
        const float linv = 1.f / l_lo;
        float lq[4];
#pragma unroll
        for (int r = 0; r < 4; ++r) lq[r] = __shfl(linv, (lane & 48) + lg * 4 + r);
#pragma unroll
        for (int dt = 0; dt < 4; ++dt)
#pragma unroll
            for (int r = 0; r < 4; ++r) {
                const int t = qb_lo * 64 + wave * 16 + lg * 4 + r;
                Aout[(((size_t)(b << 11) + t) << 10) + h * 64 + dt * 16 + lr] = f2bf(ol[dt][r] * lq[r]);
            }
    }
}

// ---------------------------------------------------------------------------
extern "C" void kernel_launch(void* const* d_in, const int* in_sizes, int n_in,
                              void* d_out, int out_size, void* d_ws, size_t ws_size,
                              hipStream_t stream) {
    (void)in_sizes; (void)n_in; (void)out_size; (void)ws_size;
    const float* x    = (const float*)d_in[0];
    const float* Wqkv = (const float*)d_in[2];
    const float* bqkv = (const float*)d_in[3];
    const float* Wout = (const float*)d_in[4];
    const float* bout = (const float*)d_in[5];
    float* out = (float*)d_out;

    char* ws = (char*)d_ws;
    u16* WqkvT = (u16*)(ws);                    //  6 MB: [3072][1024] bf16
    u16* WoutT = (u16*)(ws + 6291456);          //  2 MB: [1024][1024] bf16
    u16* xb    = (u16*)(ws + 8388608);          // 16 MB: [8192][1024] bf16
    u16* Qb    = (u16*)(ws + 25165824);         // 16 MB: [BH][T][D]
    u16* Kb    = (u16*)(ws + 41943040);         // 16 MB: [BH][T][D]
    u16* Vtb   = (u16*)(ws + 58720256);         // 16 MB: [BH][D][T]
    u16* Ab    = (u16*)(ws + 75497472);         // 16 MB: [B][T][C]

    castk<<<dim3(4096), 256, 0, stream>>>(x, xb);
    tkern<<<dim3(16 * 48), 256, 0, stream>>>(Wqkv, WqkvT, 1024, 3072);
    tkern<<<dim3(16 * 16), 256, 0, stream>>>(Wout, WoutT, 1024, 1024);
    gemm_k<0><<<dim3(64 * 24), 256, 0, stream>>>(xb, WqkvT, bqkv, Qb, Kb, Vtb, nullptr);
    flash_attn<<<dim3(16, 64), 256, 0, stream>>>(Qb, Kb, Vtb, Ab);
    gemm_k<1><<<dim3(64 * 8), 256, 0, stream>>>(Ab, WoutT, bout, nullptr, nullptr, nullptr, out);
}

// Round 4
// 336.928 us; speedup vs baseline: 1.1749x; 1.0113x over previous
//
#include <hip/hip_runtime.h>

typedef unsigned short u16;
typedef __attribute__((ext_vector_type(8))) short bf16x8;
typedef __attribute__((ext_vector_type(4))) short bf16x4;
typedef __attribute__((ext_vector_type(4))) float f32x4;

#define MFMA16(a, b, c) __builtin_amdgcn_mfma_f32_16x16x32_bf16(a, b, c, 0, 0, 0)

__device__ __forceinline__ u16 f2bf(float x) {
    unsigned u = __float_as_uint(x);
    return (u16)((u + 0x7fffu + ((u >> 16) & 1u)) >> 16);
}
__device__ __forceinline__ u16 f2bf_fast(float x) {  // round-half-up (P matrix only)
    return (u16)((__float_as_uint(x) + 0x8000u) >> 16);
}

// ---------------------------------------------------------------------------
// fp32 -> bf16 flat cast. n must be a multiple of 8*256.
// ---------------------------------------------------------------------------
__global__ __launch_bounds__(256) void castk(const float* __restrict__ src, u16* __restrict__ dst) {
    const int i = (blockIdx.x * 256 + threadIdx.x) * 8;
    float4 a = *(const float4*)(src + i);
    float4 b = *(const float4*)(src + i + 4);
    bf16x8 v;
    v[0] = (short)f2bf(a.x); v[1] = (short)f2bf(a.y);
    v[2] = (short)f2bf(a.z); v[3] = (short)f2bf(a.w);
    v[4] = (short)f2bf(b.x); v[5] = (short)f2bf(b.y);
    v[6] = (short)f2bf(b.z); v[7] = (short)f2bf(b.w);
    *(bf16x8*)(dst + i) = v;
}

// ---------------------------------------------------------------------------
// fp32 src[r][c] -> bf16 dst[c][r], 64x64 LDS tiles. grid R/64*C/64, block 256
// ---------------------------------------------------------------------------
__global__ __launch_bounds__(256) void tkern(const float* __restrict__ src, u16* __restrict__ dst,
                                             int R, int C) {
    const int tC = C >> 6;
    const int tr = (blockIdx.x / tC) << 6;
    const int tc = (blockIdx.x % tC) << 6;
    __shared__ u16 ls[64 * 68];
    const int tid = threadIdx.x;
#pragma unroll
    for (int rep = 0; rep < 2; ++rep) {
        const int f = tid * 8 + rep * 2048;
        const int r = f >> 6, c = f & 63;
        float4 a = *(const float4*)(src + (size_t)(tr + r) * C + tc + c);
        float4 b = *(const float4*)(src + (size_t)(tr + r) * C + tc + c + 4);
        bf16x4 lo, hi;
        lo[0] = (short)f2bf(a.x); lo[1] = (short)f2bf(a.y);
        lo[2] = (short)f2bf(a.z); lo[3] = (short)f2bf(a.w);
        hi[0] = (short)f2bf(b.x); hi[1] = (short)f2bf(b.y);
        hi[2] = (short)f2bf(b.z); hi[3] = (short)f2bf(b.w);
        *(bf16x4*)&ls[r * 68 + c] = lo;
        *(bf16x4*)&ls[r * 68 + c + 4] = hi;
    }
    __syncthreads();
#pragma unroll
    for (int rep = 0; rep < 2; ++rep) {
        const int f = tid * 8 + rep * 2048;
        const int rn = f >> 6, ck = f & 63;
        bf16x8 v;
#pragma unroll
        for (int j = 0; j < 8; ++j) v[j] = (short)ls[(ck + j) * 68 + rn];
        *(bf16x8*)(dst + (size_t)(tc + rn) * R + tr + ck) = v;
    }
}

// ---------------------------------------------------------------------------
// GEMM: C[m][n] = sum_k A[m][k] * Bt[n][k] + bias[n].  M=8192, K=1024, bf16.
// MODE 0: N=3072, scatter to Q(scaled)[BH][T][D], K[BH][T][D], V^T[BH][D][T].
// MODE 1: N=1024, fp32 store to Of[M][N].
// ---------------------------------------------------------------------------
template <int MODE>
__global__ __launch_bounds__(256) void gemm_k(const u16* __restrict__ A, const u16* __restrict__ Bt,
                                              const float* __restrict__ bias,
                                              u16* __restrict__ Qo, u16* __restrict__ Ko,
                                              u16* __restrict__ Vo, float* __restrict__ Of) {
    constexpr int Kd = 1024;
    const int tid = threadIdx.x;
    const int lane = tid & 63, wave = tid >> 6;
    const int wm = wave >> 1, wn = wave & 1;
    const int lr = lane & 15, lg = lane >> 4;
    const int mt = blockIdx.x & 63;
    const int nt = blockIdx.x >> 6;
    const int mbase = mt << 7, nbase = nt << 7;
    __shared__ u16 As[128 * 32];
    __shared__ u16 Bs[128 * 32];
    f32x4 acc[4][4];
#pragma unroll
    for (int i = 0; i < 4; ++i)
#pragma unroll
        for (int j = 0; j < 4; ++j) acc[i][j] = {0.f, 0.f, 0.f, 0.f};

    for (int kb = 0; kb < Kd; kb += 32) {
        __syncthreads();
#pragma unroll
        for (int rep = 0; rep < 2; ++rep) {
            const int f = tid * 8 + rep * 2048;
            const int r = f >> 5, c = f & 31;
            __builtin_amdgcn_global_load_lds(
                (const __attribute__((address_space(1))) void*)(A + (size_t)(mbase + r) * Kd + kb + c),
                (__attribute__((address_space(3))) void*)(As + f), 16, 0, 0);
            __builtin_amdgcn_global_load_lds(
                (const __attribute__((address_space(1))) void*)(Bt + (size_t)(nbase + r) * Kd + kb + c),
                (__attribute__((address_space(3))) void*)(Bs + f), 16, 0, 0);
        }
        __syncthreads();
        bf16x8 af[4], bfr[4];
#pragma unroll
        for (int i = 0; i < 4; ++i)
            af[i] = *(const bf16x8*)&As[(wm * 64 + i * 16 + lr) * 32 + lg * 8];
#pragma unroll
        for (int j = 0; j < 4; ++j)
            bfr[j] = *(const bf16x8*)&Bs[(wn * 64 + j * 16 + lr) * 32 + lg * 8];
#pragma unroll
        for (int i = 0; i < 4; ++i)
#pragma unroll
            for (int j = 0; j < 4; ++j) acc[i][j] = MFMA16(af[i], bfr[j], acc[i][j]);
    }

    const float QSCALE = 0.1803368801111137f;  // 0.125 * log2(e), folded into Q
#pragma unroll
    for (int j = 0; j < 4; ++j) {
        const int n = nbase + wn * 64 + j * 16 + lr;
        const float bj = bias[n];
        if (MODE == 0) {
            const int three = n >> 10;
            const int h = (n >> 6) & 15;
            const int d = n & 63;
#pragma unroll
            for (int i = 0; i < 4; ++i) {
#pragma unroll
                for (int r = 0; r < 4; ++r) {
                    const int m = mbase + wm * 64 + i * 16 + lg * 4 + r;
                    const int b = m >> 11, t = m & 2047;
                    const int bh = (b << 4) + h;
                    const float val = acc[i][j][r] + bj;
                    if (three == 0)
                        Qo[(((size_t)bh << 11) + t) * 64 + d] = f2bf(val * QSCALE);
                    else if (three == 1)
                        Ko[(((size_t)bh << 11) + t) * 64 + d] = f2bf(val);
                    else
                        Vo[(((size_t)bh << 6) + d) * 2048 + t] = f2bf(val);
                }
            }
        } else {
#pragma unroll
            for (int i = 0; i < 4; ++i) {
#pragma unroll
                for (int r = 0; r < 4; ++r) {
                    const int m = mbase + wm * 64 + i * 16 + lg * 4 + r;
                    Of[((size_t)m << 10) + n] = acc[i][j][r] + bj;
                }
            }
        }
    }
}

// ---------------------------------------------------------------------------
// Causal flash attention, barrier-free, register-resident K/V fragments.
// Q,K: [BH][T][D] bf16 (Q pre-scaled), Vt: [BH][D][T] bf16, Aout: [B][T][C].
// grid (16, B*H), block 128 (2 waves). Block bx pairs q-tiles qb_hi=16+bx,
// qb_lo=15-bx (perfect balance). Each wave owns 32 q of hi + 32 q of lo
// (4 subtiles); per kt it loads K/V fragments ONCE from global (L2-cached,
// q-independent lane mapping) and shares them across all subtiles. LDS is
// used only for the per-wave P round-trip (C-layout -> A-layout).
// ---------------------------------------------------------------------------
__global__ __launch_bounds__(128, 2) void flash_attn(const u16* __restrict__ Q, const u16* __restrict__ Kg,
                                                     const u16* __restrict__ Vt, u16* __restrict__ Aout) {
    const int tid = threadIdx.x;
    const int lane = tid & 63, wave = tid >> 6;  // wave 0..1
    const int lr = lane & 15, lg = lane >> 4;
    const int bx = blockIdx.x;   // 0..15
    const int bh = blockIdx.y;   // 0..63
    const int b = bh >> 4, h = bh & 15;
    const size_t base = (size_t)bh << 17;  // bh * 2048 * 64

    const int qb_hi = 16 + bx;
    const int qb_lo = 15 - bx;

    __shared__ u16 Ps[2][16 * 72];  // per-wave P scratch

    // subtile q-bases: 0,1 = hi halves; 2,3 = lo halves
    int qbase[4];
    qbase[0] = qb_hi * 64 + wave * 32;
    qbase[1] = qbase[0] + 16;
    qbase[2] = qb_lo * 64 + wave * 32;
    qbase[3] = qbase[2] + 16;

    bf16x8 qf[4][2];
#pragma unroll
    for (int st = 0; st < 4; ++st) {
        const u16* p = Q + base + (size_t)(qbase[st] + lr) * 64;
        qf[st][0] = *(const bf16x8*)(p + lg * 8);
        qf[st][1] = *(const bf16x8*)(p + 32 + lg * 8);
    }

    f32x4 o[4][4];
#pragma unroll
    for (int st = 0; st < 4; ++st)
#pragma unroll
        for (int dt = 0; dt < 4; ++dt) o[st][dt] = {0.f, 0.f, 0.f, 0.f};
    float m_[4] = {-INFINITY, -INFINITY, -INFINITY, -INFINITY};
    float l_[4] = {0.f, 0.f, 0.f, 0.f};

    // K A-frag: row kt*64 + rt*16 + lr, cols lg*8(+32). V^T B-frag: row dt*16+lr,
    // cols kt*64 + lg*8(+32). Both q-independent -> load once per kt.
    const u16* Kbase = Kg + base + (size_t)lr * 64 + lg * 8;
    const u16* Vbase = Vt + base + (size_t)lr * 2048 + lg * 8;

    for (int kt = 0; kt <= qb_hi; ++kt) {
        bf16x8 kf[4][2], vf[4][2];
        const u16* kp = Kbase + (size_t)kt * 4096;
#pragma unroll
        for (int rt = 0; rt < 4; ++rt) {
            kf[rt][0] = *(const bf16x8*)(kp + rt * 1024);
            kf[rt][1] = *(const bf16x8*)(kp + rt * 1024 + 32);
        }
        const u16* vp = Vbase + kt * 64;
#pragma unroll
        for (int dt = 0; dt < 4; ++dt) {
            vf[dt][0] = *(const bf16x8*)(vp + dt * 32768);
            vf[dt][1] = *(const bf16x8*)(vp + dt * 32768 + 32);
        }

        auto process = [&](int st, bool diag) {
            // S^T[kv][q] = K * Q^T  (kv = kt*64 + rt*16 + lg*4 + reg, q = lr)
            f32x4 s[4];
#pragma unroll
            for (int rt = 0; rt < 4; ++rt) {
                f32x4 z = {0.f, 0.f, 0.f, 0.f};
                z = MFMA16(kf[rt][0], qf[st][0], z);
                z = MFMA16(kf[rt][1], qf[st][1], z);
                s[rt] = z;
            }
            if (diag) {
                const int q_glob = qbase[st] + lr;
#pragma unroll
                for (int rt = 0; rt < 4; ++rt)
#pragma unroll
                    for (int r = 0; r < 4; ++r) {
                        const int kv = kt * 64 + rt * 16 + lg * 4 + r;
                        if (kv > q_glob) s[rt][r] = -INFINITY;
                    }
            }
            float rmax = -INFINITY;
#pragma unroll
            for (int rt = 0; rt < 4; ++rt)
#pragma unroll
                for (int r = 0; r < 4; ++r) rmax = fmaxf(rmax, s[rt][r]);
            rmax = fmaxf(rmax, __shfl_xor(rmax, 16));
            rmax = fmaxf(rmax, __shfl_xor(rmax, 32));
            const float m_new = fmaxf(m_[st], rmax);
            const float alpha = exp2f(m_[st] - m_new);
            float rsum = 0.f;
#pragma unroll
            for (int rt = 0; rt < 4; ++rt)
#pragma unroll
                for (int r = 0; r < 4; ++r) {
                    const float p = exp2f(s[rt][r] - m_new);
                    s[rt][r] = p;
                    rsum += p;
                }
            rsum += __shfl_xor(rsum, 16);
            rsum += __shfl_xor(rsum, 32);
            l_[st] = l_[st] * alpha + rsum;
            m_[st] = m_new;

            // P (C-layout) -> LDS -> A-layout frags
#pragma unroll
            for (int rt = 0; rt < 4; ++rt) {
                bf16x4 pk;
#pragma unroll
                for (int r = 0; r < 4; ++r) pk[r] = (short)f2bf_fast(s[rt][r]);
                *(bf16x4*)&Ps[wave][lr * 72 + rt * 16 + lg * 4] = pk;
            }
            float aq[4];
#pragma unroll
            for (int r = 0; r < 4; ++r) aq[r] = __shfl(alpha, (lane & 48) + lg * 4 + r);
#pragma unroll
            for (int dt = 0; dt < 4; ++dt)
#pragma unroll
                for (int r = 0; r < 4; ++r) o[st][dt][r] *= aq[r];

            const bf16x8 pf0 = *(const bf16x8*)&Ps[wave][lr * 72 + lg * 8];
            const bf16x8 pf1 = *(const bf16x8*)&Ps[wave][lr * 72 + 32 + lg * 8];
#pragma unroll
            for (int dt = 0; dt < 4; ++dt) {
                o[st][dt] = MFMA16(pf0, vf[dt][0], o[st][dt]);
                o[st][dt] = MFMA16(pf1, vf[dt][1], o[st][dt]);
            }
        };

        process(0, kt == qb_hi);
        process(1, kt == qb_hi);
        if (kt <= qb_lo) {
            process(2, kt == qb_lo);
            process(3, kt == qb_lo);
        }
    }

#pragma unroll
    for (int st = 0; st < 4; ++st) {
        const float linv = 1.f / l_[st];
        float lq[4];
#pragma unroll
        for (int r = 0; r < 4; ++r) lq[r] = __shfl(linv, (lane & 48) + lg * 4 + r);
#pragma unroll
        for (int dt = 0; dt < 4; ++dt)
#pragma unroll
            for (int r = 0; r < 4; ++r) {
                const int t = qbase[st] + lg * 4 + r;
                Aout[(((size_t)(b << 11) + t) << 10) + h * 64 + dt * 16 + lr] =
                    f2bf(o[st][dt][r] * lq[r]);
            }
    }
}

// ---------------------------------------------------------------------------
extern "C" void kernel_launch(void* const* d_in, const int* in_sizes, int n_in,
                              void* d_out, int out_size, void* d_ws, size_t ws_size,
                              hipStream_t stream) {
    (void)in_sizes; (void)n_in; (void)out_size; (void)ws_size;
    const float* x    = (const float*)d_in[0];
    const float* Wqkv = (const float*)d_in[2];
    const float* bqkv = (const float*)d_in[3];
    const float* Wout = (const float*)d_in[4];
    const float* bout = (const float*)d_in[5];
    float* out = (float*)d_out;

    char* ws = (char*)d_ws;
    u16* WqkvT = (u16*)(ws);                    //  6 MB: [3072][1024] bf16
    u16* WoutT = (u16*)(ws + 6291456);          //  2 MB: [1024][1024] bf16
    u16* xb    = (u16*)(ws + 8388608);          // 16 MB: [8192][1024] bf16
    u16* Qb    = (u16*)(ws + 25165824);         // 16 MB: [BH][T][D]
    u16* Kb    = (u16*)(ws + 41943040);         // 16 MB: [BH][T][D]
    u16* Vtb   = (u16*)(ws + 58720256);         // 16 MB: [BH][D][T]
    u16* Ab    = (u16*)(ws + 75497472);         // 16 MB: [B][T][C]

    castk<<<dim3(4096), 256, 0, stream>>>(x, xb);
    tkern<<<dim3(16 * 48), 256, 0, stream>>>(Wqkv, WqkvT, 1024, 3072);
    tkern<<<dim3(16 * 16), 256, 0, stream>>>(Wout, WoutT, 1024, 1024);
    gemm_k<0><<<dim3(64 * 24), 256, 0, stream>>>(xb, WqkvT, bqkv, Qb, Kb, Vtb, nullptr);
    flash_attn<<<dim3(16, 64), 128, 0, stream>>>(Qb, Kb, Vtb, Ab);
    gemm_k<1><<<dim3(64 * 8), 256, 0, stream>>>(Ab, WoutT, bout, nullptr, nullptr, nullptr, out);
}